// Round 1
// baseline (294.292 us; speedup 1.0000x reference)
//
#include <hip/hip_runtime.h>
#include <hip/hip_bf16.h>
#include <math.h>

#define B_   32
#define J_   1182      // V*P = 6*197
#define D_   512
#define L_   77
#define C_   5
#define JC_  64
#define NCH_ 19        // ceil(1182/64)

__device__ __forceinline__ float dot4(float4 a, float4 b) {
    return a.x*b.x + a.y*b.y + a.z*b.z + a.w*b.w;
}

__device__ __forceinline__ float wave_sum(float v) {
#pragma unroll
    for (int off = 32; off > 0; off >>= 1) v += __shfl_xor(v, off, 64);
    return v;
}

// K1: normalize feature_condition rows -> fn; loss_dis -> out[160]
__global__ void k_fn_loss(const float* __restrict__ fc, float* __restrict__ fn,
                          float* __restrict__ loss_out) {
    int wave = threadIdx.x >> 6, lane = threadIdx.x & 63;
    if (wave < C_) {
        float ss = 0.f;
        for (int d = lane; d < D_; d += 64) { float v = fc[wave*D_+d]; ss += v*v; }
        ss = wave_sum(ss);
        float inv = 1.f / fmaxf(sqrtf(ss), 1e-12f);
        for (int d = lane; d < D_; d += 64) fn[wave*D_+d] = fc[wave*D_+d]*inv;
    }
    __syncthreads();
    if (wave == 0) {
        float acc = 0.f;
        for (int i = 0; i < C_; ++i)
            for (int j = i+1; j < C_; ++j) {
                float p = 0.f;
                for (int d = lane; d < D_; d += 64) p += fn[i*D_+d]*fn[j*D_+d];
                p = wave_sum(p);
                acc += fmaxf(p, 0.f);
            }
        if (lane == 0) *loss_out = acc * (1.f/10.f);
    }
}

// K2: normalize feature_prompt rows (B*L rows of 512)
__global__ void k_norm_prompt(const float* __restrict__ fp, float* __restrict__ npb) {
    int row = blockIdx.x, lane = threadIdx.x;
    const float4* src = (const float4*)(fp + (size_t)row*D_);
    float4 a = src[lane], b = src[lane+64];
    float ss = dot4(a,a) + dot4(b,b);
    ss = wave_sum(ss);
    float inv = 1.f / fmaxf(sqrtf(ss), 1e-12f);
    a.x*=inv; a.y*=inv; a.z*=inv; a.w*=inv;
    b.x*=inv; b.y*=inv; b.z*=inv; b.w*=inv;
    float4* dst = (float4*)(npb + (size_t)row*D_);
    dst[lane] = a; dst[lane+64] = b;
}

// K3: sim_cond[b,c,l] = dot(np_prompt[b,l,:], fn[c,:])
__global__ void k_sim_cond(const float* __restrict__ npb, const float* __restrict__ fn,
                           float* __restrict__ sc) {
    int idx = blockIdx.x;               // ((b*C)+c)*L + l
    int l = idx % L_; int t = idx / L_; int c = t % C_; int b = t / C_;
    int lane = threadIdx.x;
    const float4* p = (const float4*)(npb + ((size_t)(b*L_ + l))*D_);
    const float4* q = (const float4*)(fn + c*D_);
    float s = dot4(p[lane], q[lane]) + dot4(p[lane+64], q[lane+64]);
    s = wave_sum(s);
    if (lane == 0) sc[idx] = s;
}

// K4: Q[b,c,d] = sum_l sim_cond[b,c,l] * np_prompt[b,l,d]
__global__ void k_Q(const float* __restrict__ npb, const float* __restrict__ sc,
                    float* __restrict__ Q) {
    __shared__ float s_w[L_];
    int bc = blockIdx.x; int b = bc / C_;
    int t = threadIdx.x;
    if (t < L_) s_w[t] = sc[bc*L_ + t];
    __syncthreads();
    for (int d = t; d < D_; d += 256) {
        float acc = 0.f;
        for (int l = 0; l < L_; ++l) acc += s_w[l]*npb[((size_t)(b*L_+l))*D_ + d];
        Q[bc*D_ + d] = acc;
    }
}

// K5: pw_raw[b,c,j] = (1/||tex[b,j]||) * dot(tex[b,j,:], Q[b,c,:])  [main stream #1]
__global__ void k_pw(const float* __restrict__ tex, const float* __restrict__ Q,
                     float* __restrict__ pw) {
    int j = blockIdx.x, b = blockIdx.y, lane = threadIdx.x;
    const float4* t4 = (const float4*)(tex + ((size_t)b*J_ + j)*D_);
    float4 a = t4[lane], a2 = t4[lane+64];
    float ss = dot4(a,a) + dot4(a2,a2);
    ss = wave_sum(ss);
    float inv = 1.f / fmaxf(sqrtf(ss), 1e-12f);
    float keep = 0.f;
#pragma unroll
    for (int c = 0; c < C_; ++c) {
        const float4* q4 = (const float4*)(Q + (size_t)(b*C_+c)*D_);
        float s = dot4(a, q4[lane]) + dot4(a2, q4[lane+64]);
        s = wave_sum(s);
        if (lane == c) keep = s * inv;
    }
    if (lane < C_) pw[((size_t)(b*C_+lane))*J_ + j] = keep;
}

// K6: softmax over j per (b,c), in place
__global__ void k_softmax(float* __restrict__ pw) {
    int bc = blockIdx.x;
    float* row = pw + (size_t)bc*J_;
    int t = threadIdx.x;
    __shared__ float red[256];
    float m = -1e30f;
    for (int j = t; j < J_; j += 256) m = fmaxf(m, row[j]);
    red[t] = m; __syncthreads();
    for (int s = 128; s > 0; s >>= 1) { if (t < s) red[t] = fmaxf(red[t], red[t+s]); __syncthreads(); }
    m = red[0]; __syncthreads();
    float sum = 0.f;
    for (int j = t; j < J_; j += 256) sum += expf(row[j] - m);
    red[t] = sum; __syncthreads();
    for (int s = 128; s > 0; s >>= 1) { if (t < s) red[t] += red[t+s]; __syncthreads(); }
    float inv = 1.f / red[0];
    for (int j = t; j < J_; j += 256) row[j] = expf(row[j] - m) * inv;
}

// K7: partial ftf over j-chunks  [main stream #2]
// part[chunk][b][c][d] = sum_{j in chunk} tex[b,j,d] * pw[b,c,j]
__global__ void k_ftf_part(const float* __restrict__ tex, const float* __restrict__ pw,
                           float* __restrict__ part) {
    int chunk = blockIdx.x, b = blockIdx.y;
    int t = threadIdx.x;                 // 512
    int j0 = chunk*JC_;
    int jn = min(JC_, J_ - j0);
    __shared__ float sw[C_][JC_];
    if (t < C_*JC_) {
        int c = t >> 6, jj = t & 63;
        sw[c][jj] = (jj < jn) ? pw[((size_t)(b*C_+c))*J_ + j0 + jj] : 0.f;
    }
    __syncthreads();
    float acc0=0.f, acc1=0.f, acc2=0.f, acc3=0.f, acc4=0.f;
    const float* tp = tex + ((size_t)b*J_ + j0)*D_ + t;
    for (int jj = 0; jj < jn; ++jj) {
        float v = tp[(size_t)jj*D_];
        acc0 += v*sw[0][jj]; acc1 += v*sw[1][jj]; acc2 += v*sw[2][jj];
        acc3 += v*sw[3][jj]; acc4 += v*sw[4][jj];
    }
    size_t base = (((size_t)chunk*B_ + b)*C_)*D_ + t;
    part[base          ] = acc0;
    part[base +   (size_t)D_] = acc1;
    part[base + 2*(size_t)D_] = acc2;
    part[base + 3*(size_t)D_] = acc3;
    part[base + 4*(size_t)D_] = acc4;
}

// K8: reduce partials + multiply eot -> fused[b,c,d]
__global__ void k_fused(const float* __restrict__ part, const float* __restrict__ eot,
                        float* __restrict__ fused) {
    int idx = blockIdx.x*256 + threadIdx.x;   // < B*C*D
    int d = idx & (D_-1); int bc = idx >> 9; int b = bc / C_;
    float s = 0.f;
    for (int ch = 0; ch < NCH_; ++ch) s += part[(size_t)ch*(B_*C_*D_) + idx];
    fused[idx] = s * eot[b*D_ + d];
}

// K9: fq[b,c,k] = dot(fused[b,c,:], qw[k,:]) + qb[k]
__global__ void k_fq(const float* __restrict__ fused, const float* __restrict__ qw,
                     const float* __restrict__ qb, float* __restrict__ fq) {
    int bc = blockIdx.x;
    __shared__ float sf[D_];
    int t = threadIdx.x;                 // 256
    sf[t] = fused[(size_t)bc*D_ + t];
    sf[t+256] = fused[(size_t)bc*D_ + 256 + t];
    __syncthreads();
    int wave = t >> 6, lane = t & 63;
    float4 f1 = ((const float4*)sf)[lane];
    float4 f2 = ((const float4*)sf)[lane+64];
    for (int k = wave; k < 224; k += 4) {
        const float4* w4 = (const float4*)(qw + (size_t)k*D_);
        float s = dot4(f1, w4[lane]) + dot4(f2, w4[lane+64]);
        s = wave_sum(s);
        if (lane == 0) fq[bc*224 + k] = s + qb[k];
    }
}

// K10: cond_maps[c,o] = dot(feature_condition[c,:], cw[o,:]) + cb[o]
__global__ void k_condmaps(const float* __restrict__ fc, const float* __restrict__ cw,
                           const float* __restrict__ cb, float* __restrict__ cm) {
    int idx = blockIdx.x*4 + (threadIdx.x >> 6);
    if (idx >= C_*5488) return;
    int c = idx / 5488, o = idx % 5488;
    int lane = threadIdx.x & 63;
    const float4* a4 = (const float4*)(fc + c*D_);
    const float4* w4 = (const float4*)(cw + (size_t)o*D_);
    float s = dot4(a4[lane], w4[lane]) + dot4(a4[lane+64], w4[lane+64]);
    s = wave_sum(s);
    if (lane == 0) cm[idx] = s + cb[o];
}

// K11: pooled[c,i] = mean over 7x7
__global__ void k_pooled(const float* __restrict__ cm, float* __restrict__ pooled) {
    int t = blockIdx.x*blockDim.x + threadIdx.x;
    if (t >= C_*112) return;
    int c = t / 112, i = t % 112;
    const float* p = cm + c*5488 + i*49;
    float s = 0.f;
    for (int k = 0; k < 49; ++k) s += p[k];
    pooled[t] = s * (1.f/49.f);
}

// K12: all four 3x3 SAME convs on [C,112,7,7], thread per output point
__global__ void k_conv(const float* __restrict__ cm,
                       const float* __restrict__ w1, const float* __restrict__ bb1,
                       const float* __restrict__ w2, const float* __restrict__ bb2,
                       const float* __restrict__ w3, const float* __restrict__ bb3,
                       const float* __restrict__ w4, const float* __restrict__ bb4,
                       float* __restrict__ o1, float* __restrict__ o2,
                       float* __restrict__ o3, float* __restrict__ o4) {
    const int N1 = C_*512*49, N2 = C_*128*49, N3 = C_*32*49, N4 = C_*8*49;
    int tid = blockIdx.x*blockDim.x + threadIdx.x;
    const float* w; const float* bias; float* out; int O; int rel;
    if      (tid < N1)          { w=w1; bias=bb1; out=o1; O=512; rel=tid; }
    else if (tid < N1+N2)       { w=w2; bias=bb2; out=o2; O=128; rel=tid-N1; }
    else if (tid < N1+N2+N3)    { w=w3; bias=bb3; out=o3; O=32;  rel=tid-N1-N2; }
    else if (tid < N1+N2+N3+N4) { w=w4; bias=bb4; out=o4; O=8;   rel=tid-N1-N2-N3; }
    else return;
    int per_c = O*49;
    int c = rel / per_c; int r = rel % per_c;
    int o = r / 49; int yx = r % 49; int y = yx / 7; int x = yx % 7;
    float s = bias[o];
    const float* cmc = cm + c*5488;
    const float* wo  = w + (size_t)o*112*9;
    for (int ch = 0; ch < 112; ++ch) {
        const float* im = cmc + ch*49;
        const float* wk = wo + ch*9;
#pragma unroll
        for (int ky = 0; ky < 3; ++ky) {
            int yy = y + ky - 1;
            if ((unsigned)yy > 6u) continue;
#pragma unroll
            for (int kx = 0; kx < 3; ++kx) {
                int xx = x + kx - 1;
                if ((unsigned)xx > 6u) continue;
                s += im[yy*7+xx]*wk[ky*3+kx];
            }
        }
    }
    out[rel] = s;
}

// K13: hypernet fc biases (and fc5w/fc5b), thread per output
// fcb layout: [0,560) fc1b | [560,840) fc2b | [840,980) fc3b | [980,1050) fc4b
//             [1050,1120) fc5w | [1120,1125) fc5b
__global__ void k_hbias(const float* __restrict__ pooled,
                        const float* __restrict__ w1b, const float* __restrict__ b1b,
                        const float* __restrict__ w2b, const float* __restrict__ b2b,
                        const float* __restrict__ w3b, const float* __restrict__ b3b,
                        const float* __restrict__ w4b, const float* __restrict__ b4b,
                        const float* __restrict__ w5w, const float* __restrict__ b5w,
                        const float* __restrict__ w5b, const float* __restrict__ b5b,
                        float* __restrict__ fcb) {
    int tid = blockIdx.x*blockDim.x + threadIdx.x;
    if (tid >= 1125) return;
    const float* w; const float* bb; int nout; int base; int rel = tid;
    if      (rel < 560)  { w=w1b; bb=b1b; nout=112; base=0; }
    else if (rel < 840)  { rel-=560;  w=w2b; bb=b2b; nout=56; base=560; }
    else if (rel < 980)  { rel-=840;  w=w3b; bb=b3b; nout=28; base=840; }
    else if (rel < 1050) { rel-=980;  w=w4b; bb=b4b; nout=14; base=980; }
    else if (rel < 1120) { rel-=1050; w=w5w; bb=b5w; nout=14; base=1050; }
    else                 { rel-=1120; w=w5b; bb=b5b; nout=1;  base=1120; }
    int c = rel / nout; int jo = rel % nout;
    const float* p = pooled + c*112;
    float s = bb[jo];
    for (int i = 0; i < 112; ++i) s += p[i]*w[jo*112+i];
    fcb[base + rel] = s;
}

// K14: TargetNet per (b,c): 4 sigmoid layers + linear head -> out[b*C+c]
__global__ void k_target(const float* __restrict__ fq,
                         const float* __restrict__ g1w, const float* __restrict__ g2w,
                         const float* __restrict__ g3w, const float* __restrict__ g4w,
                         const float* __restrict__ fcb, float* __restrict__ out) {
    int c = blockIdx.x, b = blockIdx.y;
    __shared__ float sa[224], sb[112];
    int t = threadIdx.x;                 // 128
    for (int k = t; k < 224; k += 128) sa[k] = fq[(size_t)(b*C_+c)*224 + k];
    __syncthreads();
    if (t < 112) {
        const float* w = g1w + (size_t)c*25088 + t*224;
        float s = fcb[c*112 + t];
        for (int k = 0; k < 224; ++k) s += w[k]*sa[k];
        sb[t] = 1.f/(1.f+expf(-s));
    }
    __syncthreads();
    if (t < 56) {
        const float* w = g2w + (size_t)c*6272 + t*112;
        float s = fcb[560 + c*56 + t];
        for (int k = 0; k < 112; ++k) s += w[k]*sb[k];
        sa[t] = 1.f/(1.f+expf(-s));
    }
    __syncthreads();
    if (t < 28) {
        const float* w = g3w + (size_t)c*1568 + t*56;
        float s = fcb[840 + c*28 + t];
        for (int k = 0; k < 56; ++k) s += w[k]*sa[k];
        sb[t] = 1.f/(1.f+expf(-s));
    }
    __syncthreads();
    if (t < 14) {
        const float* w = g4w + (size_t)c*392 + t*28;
        float s = fcb[980 + c*14 + t];
        for (int k = 0; k < 28; ++k) s += w[k]*sb[k];
        sa[t] = 1.f/(1.f+expf(-s));
    }
    __syncthreads();
    if (t == 0) {
        float s = fcb[1120 + c];
        for (int p = 0; p < 14; ++p) s += sa[p]*fcb[1050 + c*14 + p];
        out[b*C_ + c] = s;
    }
}

extern "C" void kernel_launch(void* const* d_in, const int* in_sizes, int n_in,
                              void* d_out, int out_size, void* d_ws, size_t ws_size,
                              hipStream_t stream) {
    (void)in_sizes; (void)n_in; (void)out_size; (void)ws_size;
    const float* tex   = (const float*)d_in[0];
    const float* fp    = (const float*)d_in[1];
    const float* eot   = (const float*)d_in[2];
    const float* fcond = (const float*)d_in[3];
    const float* qw    = (const float*)d_in[4];
    const float* qb    = (const float*)d_in[5];
    const float* cw    = (const float*)d_in[6];
    const float* cb    = (const float*)d_in[7];
    const float* w1c   = (const float*)d_in[8];  const float* b1c = (const float*)d_in[9];
    const float* w2c   = (const float*)d_in[10]; const float* b2c = (const float*)d_in[11];
    const float* w3c   = (const float*)d_in[12]; const float* b3c = (const float*)d_in[13];
    const float* w4c   = (const float*)d_in[14]; const float* b4c = (const float*)d_in[15];
    const float* f1bw  = (const float*)d_in[16]; const float* f1bb = (const float*)d_in[17];
    const float* f2bw  = (const float*)d_in[18]; const float* f2bb = (const float*)d_in[19];
    const float* f3bw  = (const float*)d_in[20]; const float* f3bb = (const float*)d_in[21];
    const float* f4bw  = (const float*)d_in[22]; const float* f4bb = (const float*)d_in[23];
    const float* f5ww  = (const float*)d_in[24]; const float* f5wb = (const float*)d_in[25];
    const float* f5bw  = (const float*)d_in[26]; const float* f5bb = (const float*)d_in[27];
    float* out = (float*)d_out;

    float* ws     = (float*)d_ws;
    float* fn     = ws;                         // 2560
    float* npb    = fn + 2560;                  // 1261568
    float* sc     = npb + 1261568;              // 12320
    float* Qb     = sc + 12320;                 // 81920
    float* pw     = Qb + 81920;                 // 189120
    float* part   = pw + 189120;                // NCH*81920
    float* fused  = part + (size_t)NCH_*81920;  // 81920
    float* fqb    = fused + 81920;              // 35840
    float* cm     = fqb + 35840;                // 27440
    float* pooled = cm + 27440;                 // 560
    float* g1w    = pooled + 560;               // 125440
    float* g2w    = g1w + 125440;               // 31360
    float* g3w    = g2w + 31360;                // 7840
    float* g4w    = g3w + 7840;                 // 1960
    float* fcb    = g4w + 1960;                 // 1125

    // condition path
    k_fn_loss<<<1, 320, 0, stream>>>(fcond, fn, out + B_*C_);
    k_condmaps<<<(C_*5488)/4, 256, 0, stream>>>(fcond, cw, cb, cm);
    k_pooled<<<3, 256, 0, stream>>>(cm, pooled);
    k_conv<<<651, 256, 0, stream>>>(cm, w1c, b1c, w2c, b2c, w3c, b3c, w4c, b4c,
                                    g1w, g2w, g3w, g4w);
    k_hbias<<<5, 256, 0, stream>>>(pooled, f1bw, f1bb, f2bw, f2bb, f3bw, f3bb,
                                   f4bw, f4bb, f5ww, f5wb, f5bw, f5bb, fcb);

    // main path
    k_norm_prompt<<<B_*L_, 64, 0, stream>>>(fp, npb);
    k_sim_cond<<<B_*C_*L_, 64, 0, stream>>>(npb, fn, sc);
    k_Q<<<B_*C_, 256, 0, stream>>>(npb, sc, Qb);
    k_pw<<<dim3(J_, B_), 64, 0, stream>>>(tex, Qb, pw);
    k_softmax<<<B_*C_, 256, 0, stream>>>(pw);
    k_ftf_part<<<dim3(NCH_, B_), 512, 0, stream>>>(tex, pw, part);
    k_fused<<<(B_*C_*D_)/256, 256, 0, stream>>>(part, eot, fused);
    k_fq<<<B_*C_, 256, 0, stream>>>(fused, qw, qb, fqb);
    k_target<<<dim3(C_, B_), 128, 0, stream>>>(fqb, g1w, g2w, g3w, g4w, fcb, out);
}

// Round 2
// 195.646 us; speedup vs baseline: 1.5042x; 1.5042x over previous
//
#include <hip/hip_runtime.h>
#include <hip/hip_bf16.h>
#include <math.h>

#define B_   32
#define J_   1182      // V*P = 6*197
#define D_   512
#define L_   77
#define C_   5
#define JC_  64
#define NCH_ 19        // ceil(1182/64)

__device__ __forceinline__ float dot4(float4 a, float4 b) {
    return a.x*b.x + a.y*b.y + a.z*b.z + a.w*b.w;
}

__device__ __forceinline__ float wave_sum(float v) {
#pragma unroll
    for (int off = 32; off > 0; off >>= 1) v += __shfl_xor(v, off, 64);
    return v;
}

// K1: normalize feature_condition rows -> fn; loss_dis -> out[160]
__global__ void k_fn_loss(const float* __restrict__ fc, float* __restrict__ fn,
                          float* __restrict__ loss_out) {
    int wave = threadIdx.x >> 6, lane = threadIdx.x & 63;
    if (wave < C_) {
        float ss = 0.f;
        for (int d = lane; d < D_; d += 64) { float v = fc[wave*D_+d]; ss += v*v; }
        ss = wave_sum(ss);
        float inv = 1.f / fmaxf(sqrtf(ss), 1e-12f);
        for (int d = lane; d < D_; d += 64) fn[wave*D_+d] = fc[wave*D_+d]*inv;
    }
    __syncthreads();
    if (wave == 0) {
        float acc = 0.f;
        for (int i = 0; i < C_; ++i)
            for (int j = i+1; j < C_; ++j) {
                float p = 0.f;
                for (int d = lane; d < D_; d += 64) p += fn[i*D_+d]*fn[j*D_+d];
                p = wave_sum(p);
                acc += fmaxf(p, 0.f);
            }
        if (lane == 0) *loss_out = acc * (1.f/10.f);
    }
}

// K2: normalize feature_prompt rows (B*L rows of 512)
__global__ void k_norm_prompt(const float* __restrict__ fp, float* __restrict__ npb) {
    int row = blockIdx.x, lane = threadIdx.x;
    const float4* src = (const float4*)(fp + (size_t)row*D_);
    float4 a = src[lane], b = src[lane+64];
    float ss = dot4(a,a) + dot4(b,b);
    ss = wave_sum(ss);
    float inv = 1.f / fmaxf(sqrtf(ss), 1e-12f);
    a.x*=inv; a.y*=inv; a.z*=inv; a.w*=inv;
    b.x*=inv; b.y*=inv; b.z*=inv; b.w*=inv;
    float4* dst = (float4*)(npb + (size_t)row*D_);
    dst[lane] = a; dst[lane+64] = b;
}

// K3: sim_cond[b,c,l] = dot(np_prompt[b,l,:], fn[c,:])
__global__ void k_sim_cond(const float* __restrict__ npb, const float* __restrict__ fn,
                           float* __restrict__ sc) {
    int idx = blockIdx.x;               // ((b*C)+c)*L + l
    int l = idx % L_; int t = idx / L_; int c = t % C_; int b = t / C_;
    int lane = threadIdx.x;
    const float4* p = (const float4*)(npb + ((size_t)(b*L_ + l))*D_);
    const float4* q = (const float4*)(fn + c*D_);
    float s = dot4(p[lane], q[lane]) + dot4(p[lane+64], q[lane+64]);
    s = wave_sum(s);
    if (lane == 0) sc[idx] = s;
}

// K4: Q[b,c,d] = sum_l sim_cond[b,c,l] * np_prompt[b,l,d]
__global__ void k_Q(const float* __restrict__ npb, const float* __restrict__ sc,
                    float* __restrict__ Q) {
    __shared__ float s_w[L_];
    int bc = blockIdx.x; int b = bc / C_;
    int t = threadIdx.x;
    if (t < L_) s_w[t] = sc[bc*L_ + t];
    __syncthreads();
    for (int d = t; d < D_; d += 256) {
        float acc = 0.f;
        for (int l = 0; l < L_; ++l) acc += s_w[l]*npb[((size_t)(b*L_+l))*D_ + d];
        Q[bc*D_ + d] = acc;
    }
}

// K5: pw_raw[b,c,j] = (1/||tex[b,j]||) * dot(tex[b,j,:], Q[b,c,:])  [main stream #1]
__global__ void k_pw(const float* __restrict__ tex, const float* __restrict__ Q,
                     float* __restrict__ pw) {
    int j = blockIdx.x, b = blockIdx.y, lane = threadIdx.x;
    const float4* t4 = (const float4*)(tex + ((size_t)b*J_ + j)*D_);
    float4 a = t4[lane], a2 = t4[lane+64];
    float ss = dot4(a,a) + dot4(a2,a2);
    ss = wave_sum(ss);
    float inv = 1.f / fmaxf(sqrtf(ss), 1e-12f);
    float keep = 0.f;
#pragma unroll
    for (int c = 0; c < C_; ++c) {
        const float4* q4 = (const float4*)(Q + (size_t)(b*C_+c)*D_);
        float s = dot4(a, q4[lane]) + dot4(a2, q4[lane+64]);
        s = wave_sum(s);
        if (lane == c) keep = s * inv;
    }
    if (lane < C_) pw[((size_t)(b*C_+lane))*J_ + j] = keep;
}

// K6: softmax over j per (b,c), in place
__global__ void k_softmax(float* __restrict__ pw) {
    int bc = blockIdx.x;
    float* row = pw + (size_t)bc*J_;
    int t = threadIdx.x;
    __shared__ float red[256];
    float m = -1e30f;
    for (int j = t; j < J_; j += 256) m = fmaxf(m, row[j]);
    red[t] = m; __syncthreads();
    for (int s = 128; s > 0; s >>= 1) { if (t < s) red[t] = fmaxf(red[t], red[t+s]); __syncthreads(); }
    m = red[0]; __syncthreads();
    float sum = 0.f;
    for (int j = t; j < J_; j += 256) sum += expf(row[j] - m);
    red[t] = sum; __syncthreads();
    for (int s = 128; s > 0; s >>= 1) { if (t < s) red[t] += red[t+s]; __syncthreads(); }
    float inv = 1.f / red[0];
    for (int j = t; j < J_; j += 256) row[j] = expf(row[j] - m) * inv;
}

// K7: partial ftf over j-chunks  [main stream #2]
// part[chunk][b][c][d] = sum_{j in chunk} tex[b,j,d] * pw[b,c,j]
__global__ void k_ftf_part(const float* __restrict__ tex, const float* __restrict__ pw,
                           float* __restrict__ part) {
    int chunk = blockIdx.x, b = blockIdx.y;
    int t = threadIdx.x;                 // 512
    int j0 = chunk*JC_;
    int jn = min(JC_, J_ - j0);
    __shared__ float sw[C_][JC_];
    if (t < C_*JC_) {
        int c = t >> 6, jj = t & 63;
        sw[c][jj] = (jj < jn) ? pw[((size_t)(b*C_+c))*J_ + j0 + jj] : 0.f;
    }
    __syncthreads();
    float acc0=0.f, acc1=0.f, acc2=0.f, acc3=0.f, acc4=0.f;
    const float* tp = tex + ((size_t)b*J_ + j0)*D_ + t;
    for (int jj = 0; jj < jn; ++jj) {
        float v = tp[(size_t)jj*D_];
        acc0 += v*sw[0][jj]; acc1 += v*sw[1][jj]; acc2 += v*sw[2][jj];
        acc3 += v*sw[3][jj]; acc4 += v*sw[4][jj];
    }
    size_t base = (((size_t)chunk*B_ + b)*C_)*D_ + t;
    part[base          ] = acc0;
    part[base +   (size_t)D_] = acc1;
    part[base + 2*(size_t)D_] = acc2;
    part[base + 3*(size_t)D_] = acc3;
    part[base + 4*(size_t)D_] = acc4;
}

// K8: reduce partials + multiply eot -> fused[b,c,d]
__global__ void k_fused(const float* __restrict__ part, const float* __restrict__ eot,
                        float* __restrict__ fused) {
    int idx = blockIdx.x*256 + threadIdx.x;   // < B*C*D
    int d = idx & (D_-1); int bc = idx >> 9; int b = bc / C_;
    float s = 0.f;
    for (int ch = 0; ch < NCH_; ++ch) s += part[(size_t)ch*(B_*C_*D_) + idx];
    fused[idx] = s * eot[b*D_ + d];
}

// K9: fq[b,c,k] = dot(fused[b,c,:], qw[k,:]) + qb[k]
__global__ void k_fq(const float* __restrict__ fused, const float* __restrict__ qw,
                     const float* __restrict__ qb, float* __restrict__ fq) {
    int bc = blockIdx.x;
    __shared__ float sf[D_];
    int t = threadIdx.x;                 // 256
    sf[t] = fused[(size_t)bc*D_ + t];
    sf[t+256] = fused[(size_t)bc*D_ + 256 + t];
    __syncthreads();
    int wave = t >> 6, lane = t & 63;
    float4 f1 = ((const float4*)sf)[lane];
    float4 f2 = ((const float4*)sf)[lane+64];
    for (int k = wave; k < 224; k += 4) {
        const float4* w4 = (const float4*)(qw + (size_t)k*D_);
        float s = dot4(f1, w4[lane]) + dot4(f2, w4[lane+64]);
        s = wave_sum(s);
        if (lane == 0) fq[bc*224 + k] = s + qb[k];
    }
}

// K10: cond_maps[c,o] = dot(feature_condition[c,:], cw[o,:]) + cb[o]
__global__ void k_condmaps(const float* __restrict__ fc, const float* __restrict__ cw,
                           const float* __restrict__ cb, float* __restrict__ cm) {
    int idx = blockIdx.x*4 + (threadIdx.x >> 6);
    if (idx >= C_*5488) return;
    int c = idx / 5488, o = idx % 5488;
    int lane = threadIdx.x & 63;
    const float4* a4 = (const float4*)(fc + c*D_);
    const float4* w4 = (const float4*)(cw + (size_t)o*D_);
    float s = dot4(a4[lane], w4[lane]) + dot4(a4[lane+64], w4[lane+64]);
    s = wave_sum(s);
    if (lane == 0) cm[idx] = s + cb[o];
}

// K11: pooled[c,i] = mean over 7x7
__global__ void k_pooled(const float* __restrict__ cm, float* __restrict__ pooled) {
    int t = blockIdx.x*blockDim.x + threadIdx.x;
    if (t >= C_*112) return;
    int c = t / 112, i = t % 112;
    const float* p = cm + c*5488 + i*49;
    float s = 0.f;
    for (int k = 0; k < 49; ++k) s += p[k];
    pooled[t] = s * (1.f/49.f);
}

// K12: all four 3x3 SAME convs on [C,112,7,7].
// Branch-free: stage cm[c] in LDS zero-padded to 9x9, fully unroll 3x3.
// grid: dim3(131, C_), block 256; one thread per output point over the
// combined 680-channel output space (512+128+32+8), 49 points each.
__global__ void k_conv(const float* __restrict__ cm,
                       const float* __restrict__ w1, const float* __restrict__ bb1,
                       const float* __restrict__ w2, const float* __restrict__ bb2,
                       const float* __restrict__ w3, const float* __restrict__ bb3,
                       const float* __restrict__ w4, const float* __restrict__ bb4,
                       float* __restrict__ o1, float* __restrict__ o2,
                       float* __restrict__ o3, float* __restrict__ o4) {
    __shared__ float im[112*81];         // 9x9 zero-padded per channel
    int c = blockIdx.y;
    int t = threadIdx.x;
    for (int i = t; i < 112*81; i += 256) im[i] = 0.f;
    __syncthreads();
    const float* cmc = cm + c*5488;
    for (int i = t; i < 112*49; i += 256) {
        int ch = i / 49, yx = i - ch*49;
        int y = yx / 7, x = yx - y*7;
        im[ch*81 + (y+1)*9 + (x+1)] = cmc[i];
    }
    __syncthreads();

    int gout = blockIdx.x*256 + t;       // < 680*49 = 33320
    if (gout >= 680*49) return;
    int o_comb = gout / 49;
    int yx = gout - o_comb*49;
    int y = yx / 7, x = yx - y*7;

    const float* w; const float* bias; float* outp; int o;
    if      (o_comb < 512) { w=w1; bias=bb1; outp=o1 + (size_t)c*512*49; o=o_comb; }
    else if (o_comb < 640) { w=w2; bias=bb2; outp=o2 + (size_t)c*128*49; o=o_comb-512; }
    else if (o_comb < 672) { w=w3; bias=bb3; outp=o3 + (size_t)c*32*49;  o=o_comb-640; }
    else                   { w=w4; bias=bb4; outp=o4 + (size_t)c*8*49;   o=o_comb-672; }

    float s = bias[o];
    const float* wo = w + (size_t)o*112*9;
#pragma unroll 4
    for (int ch = 0; ch < 112; ++ch) {
        const float* ii = im + ch*81 + y*9 + x;   // tap (ky,kx) -> ii[ky*9+kx]
        const float* wk = wo + ch*9;
#pragma unroll
        for (int ky = 0; ky < 3; ++ky) {
#pragma unroll
            for (int kx = 0; kx < 3; ++kx) {
                s += ii[ky*9+kx] * wk[ky*3+kx];
            }
        }
    }
    outp[o*49 + yx] = s;
}

// K13: hypernet fc biases (and fc5w/fc5b), thread per output
// fcb layout: [0,560) fc1b | [560,840) fc2b | [840,980) fc3b | [980,1050) fc4b
//             [1050,1120) fc5w | [1120,1125) fc5b
__global__ void k_hbias(const float* __restrict__ pooled,
                        const float* __restrict__ w1b, const float* __restrict__ b1b,
                        const float* __restrict__ w2b, const float* __restrict__ b2b,
                        const float* __restrict__ w3b, const float* __restrict__ b3b,
                        const float* __restrict__ w4b, const float* __restrict__ b4b,
                        const float* __restrict__ w5w, const float* __restrict__ b5w,
                        const float* __restrict__ w5b, const float* __restrict__ b5b,
                        float* __restrict__ fcb) {
    int tid = blockIdx.x*blockDim.x + threadIdx.x;
    if (tid >= 1125) return;
    const float* w; const float* bb; int nout; int base; int rel = tid;
    if      (rel < 560)  { w=w1b; bb=b1b; nout=112; base=0; }
    else if (rel < 840)  { rel-=560;  w=w2b; bb=b2b; nout=56; base=560; }
    else if (rel < 980)  { rel-=840;  w=w3b; bb=b3b; nout=28; base=840; }
    else if (rel < 1050) { rel-=980;  w=w4b; bb=b4b; nout=14; base=980; }
    else if (rel < 1120) { rel-=1050; w=w5w; bb=b5w; nout=14; base=1050; }
    else                 { rel-=1120; w=w5b; bb=b5b; nout=1;  base=1120; }
    int c = rel / nout; int jo = rel % nout;
    const float* p = pooled + c*112;
    float s = bb[jo];
    for (int i = 0; i < 112; ++i) s += p[i]*w[jo*112+i];
    fcb[base + rel] = s;
}

// K14: TargetNet per (b,c): 4 sigmoid layers + linear head -> out[b*C+c]
__global__ void k_target(const float* __restrict__ fq,
                         const float* __restrict__ g1w, const float* __restrict__ g2w,
                         const float* __restrict__ g3w, const float* __restrict__ g4w,
                         const float* __restrict__ fcb, float* __restrict__ out) {
    int c = blockIdx.x, b = blockIdx.y;
    __shared__ float sa[224], sb[112];
    int t = threadIdx.x;                 // 128
    for (int k = t; k < 224; k += 128) sa[k] = fq[(size_t)(b*C_+c)*224 + k];
    __syncthreads();
    if (t < 112) {
        const float* w = g1w + (size_t)c*25088 + t*224;
        float s = fcb[c*112 + t];
        for (int k = 0; k < 224; ++k) s += w[k]*sa[k];
        sb[t] = 1.f/(1.f+expf(-s));
    }
    __syncthreads();
    if (t < 56) {
        const float* w = g2w + (size_t)c*6272 + t*112;
        float s = fcb[560 + c*56 + t];
        for (int k = 0; k < 112; ++k) s += w[k]*sb[k];
        sa[t] = 1.f/(1.f+expf(-s));
    }
    __syncthreads();
    if (t < 28) {
        const float* w = g3w + (size_t)c*1568 + t*56;
        float s = fcb[840 + c*28 + t];
        for (int k = 0; k < 56; ++k) s += w[k]*sa[k];
        sb[t] = 1.f/(1.f+expf(-s));
    }
    __syncthreads();
    if (t < 14) {
        const float* w = g4w + (size_t)c*392 + t*28;
        float s = fcb[980 + c*14 + t];
        for (int k = 0; k < 28; ++k) s += w[k]*sb[k];
        sa[t] = 1.f/(1.f+expf(-s));
    }
    __syncthreads();
    if (t == 0) {
        float s = fcb[1120 + c];
        for (int p = 0; p < 14; ++p) s += sa[p]*fcb[1050 + c*14 + p];
        out[b*C_ + c] = s;
    }
}

extern "C" void kernel_launch(void* const* d_in, const int* in_sizes, int n_in,
                              void* d_out, int out_size, void* d_ws, size_t ws_size,
                              hipStream_t stream) {
    (void)in_sizes; (void)n_in; (void)out_size; (void)ws_size;
    const float* tex   = (const float*)d_in[0];
    const float* fp    = (const float*)d_in[1];
    const float* eot   = (const float*)d_in[2];
    const float* fcond = (const float*)d_in[3];
    const float* qw    = (const float*)d_in[4];
    const float* qb    = (const float*)d_in[5];
    const float* cw    = (const float*)d_in[6];
    const float* cb    = (const float*)d_in[7];
    const float* w1c   = (const float*)d_in[8];  const float* b1c = (const float*)d_in[9];
    const float* w2c   = (const float*)d_in[10]; const float* b2c = (const float*)d_in[11];
    const float* w3c   = (const float*)d_in[12]; const float* b3c = (const float*)d_in[13];
    const float* w4c   = (const float*)d_in[14]; const float* b4c = (const float*)d_in[15];
    const float* f1bw  = (const float*)d_in[16]; const float* f1bb = (const float*)d_in[17];
    const float* f2bw  = (const float*)d_in[18]; const float* f2bb = (const float*)d_in[19];
    const float* f3bw  = (const float*)d_in[20]; const float* f3bb = (const float*)d_in[21];
    const float* f4bw  = (const float*)d_in[22]; const float* f4bb = (const float*)d_in[23];
    const float* f5ww  = (const float*)d_in[24]; const float* f5wb = (const float*)d_in[25];
    const float* f5bw  = (const float*)d_in[26]; const float* f5bb = (const float*)d_in[27];
    float* out = (float*)d_out;

    float* ws     = (float*)d_ws;
    float* fn     = ws;                         // 2560
    float* npb    = fn + 2560;                  // 1261568
    float* sc     = npb + 1261568;              // 12320
    float* Qb     = sc + 12320;                 // 81920
    float* pw     = Qb + 81920;                 // 189120
    float* part   = pw + 189120;                // NCH*81920
    float* fused  = part + (size_t)NCH_*81920;  // 81920
    float* fqb    = fused + 81920;              // 35840
    float* cm     = fqb + 35840;                // 27440
    float* pooled = cm + 27440;                 // 560
    float* g1w    = pooled + 560;               // 125440
    float* g2w    = g1w + 125440;               // 31360
    float* g3w    = g2w + 31360;                // 7840
    float* g4w    = g3w + 7840;                 // 1960
    float* fcb    = g4w + 1960;                 // 1125

    // condition path
    k_fn_loss<<<1, 320, 0, stream>>>(fcond, fn, out + B_*C_);
    k_condmaps<<<(C_*5488)/4, 256, 0, stream>>>(fcond, cw, cb, cm);
    k_pooled<<<3, 256, 0, stream>>>(cm, pooled);
    k_conv<<<dim3(131, C_), 256, 0, stream>>>(cm, w1c, b1c, w2c, b2c, w3c, b3c, w4c, b4c,
                                              g1w, g2w, g3w, g4w);
    k_hbias<<<5, 256, 0, stream>>>(pooled, f1bw, f1bb, f2bw, f2bb, f3bw, f3bb,
                                   f4bw, f4bb, f5ww, f5wb, f5bw, f5bb, fcb);

    // main path
    k_norm_prompt<<<B_*L_, 64, 0, stream>>>(fp, npb);
    k_sim_cond<<<B_*C_*L_, 64, 0, stream>>>(npb, fn, sc);
    k_Q<<<B_*C_, 256, 0, stream>>>(npb, sc, Qb);
    k_pw<<<dim3(J_, B_), 64, 0, stream>>>(tex, Qb, pw);
    k_softmax<<<B_*C_, 256, 0, stream>>>(pw);
    k_ftf_part<<<dim3(NCH_, B_), 512, 0, stream>>>(tex, pw, part);
    k_fused<<<(B_*C_*D_)/256, 256, 0, stream>>>(part, eot, fused);
    k_fq<<<B_*C_, 256, 0, stream>>>(fused, qw, qb, fqb);
    k_target<<<dim3(C_, B_), 128, 0, stream>>>(fqb, g1w, g2w, g3w, g4w, fcb, out);
}

// Round 3
// 150.083 us; speedup vs baseline: 1.9609x; 1.3036x over previous
//
#include <hip/hip_runtime.h>
#include <hip/hip_bf16.h>
#include <math.h>

#define B_   32
#define J_   1182      // V*P = 6*197
#define D_   512
#define L_   77
#define C_   5
#define JC_  64
#define NCH_ 19        // ceil(1182/64)

__device__ __forceinline__ float dot4(float4 a, float4 b) {
    return a.x*b.x + a.y*b.y + a.z*b.z + a.w*b.w;
}

__device__ __forceinline__ float wave_sum(float v) {
#pragma unroll
    for (int off = 32; off > 0; off >>= 1) v += __shfl_xor(v, off, 64);
    return v;
}

// K1: normalize feature_condition rows -> fn; loss_dis -> out[160]
__global__ void k_fn_loss(const float* __restrict__ fc, float* __restrict__ fn,
                          float* __restrict__ loss_out) {
    int wave = threadIdx.x >> 6, lane = threadIdx.x & 63;
    if (wave < C_) {
        float ss = 0.f;
        for (int d = lane; d < D_; d += 64) { float v = fc[wave*D_+d]; ss += v*v; }
        ss = wave_sum(ss);
        float inv = 1.f / fmaxf(sqrtf(ss), 1e-12f);
        for (int d = lane; d < D_; d += 64) fn[wave*D_+d] = fc[wave*D_+d]*inv;
    }
    __syncthreads();
    if (wave == 0) {
        float acc = 0.f;
        for (int i = 0; i < C_; ++i)
            for (int j = i+1; j < C_; ++j) {
                float p = 0.f;
                for (int d = lane; d < D_; d += 64) p += fn[i*D_+d]*fn[j*D_+d];
                p = wave_sum(p);
                acc += fmaxf(p, 0.f);
            }
        if (lane == 0) *loss_out = acc * (1.f/10.f);
    }
}

// K2: normalize feature_prompt rows (B*L rows of 512)
__global__ void k_norm_prompt(const float* __restrict__ fp, float* __restrict__ npb) {
    int row = blockIdx.x, lane = threadIdx.x;
    const float4* src = (const float4*)(fp + (size_t)row*D_);
    float4 a = src[lane], b = src[lane+64];
    float ss = dot4(a,a) + dot4(b,b);
    ss = wave_sum(ss);
    float inv = 1.f / fmaxf(sqrtf(ss), 1e-12f);
    a.x*=inv; a.y*=inv; a.z*=inv; a.w*=inv;
    b.x*=inv; b.y*=inv; b.z*=inv; b.w*=inv;
    float4* dst = (float4*)(npb + (size_t)row*D_);
    dst[lane] = a; dst[lane+64] = b;
}

// K3: sim_cond[b,c,l] = dot(np_prompt[b,l,:], fn[c,:])
__global__ void k_sim_cond(const float* __restrict__ npb, const float* __restrict__ fn,
                           float* __restrict__ sc) {
    int idx = blockIdx.x;               // ((b*C)+c)*L + l
    int l = idx % L_; int t = idx / L_; int c = t % C_; int b = t / C_;
    int lane = threadIdx.x;
    const float4* p = (const float4*)(npb + ((size_t)(b*L_ + l))*D_);
    const float4* q = (const float4*)(fn + c*D_);
    float s = dot4(p[lane], q[lane]) + dot4(p[lane+64], q[lane+64]);
    s = wave_sum(s);
    if (lane == 0) sc[idx] = s;
}

// K4: Q[b,c,d] = sum_l sim_cond[b,c,l] * np_prompt[b,l,d]
// one block per b, thread owns float2 (dims 2t, 2t+1), 5 accumulators
__global__ void k_Q(const float* __restrict__ npb, const float* __restrict__ sc,
                    float* __restrict__ Q) {
    __shared__ float sw[C_][80];
    int b = blockIdx.x;
    int t = threadIdx.x;                 // 256
    for (int i = t; i < C_*L_; i += 256) { int c = i/L_, l = i - c*L_; sw[c][l] = sc[(b*C_+c)*L_ + l]; }
    __syncthreads();
    float2 a0={0,0}, a1={0,0}, a2={0,0}, a3={0,0}, a4={0,0};
    const float2* np2 = (const float2*)(npb + (size_t)b*L_*D_) + t;
    for (int l = 0; l < L_; ++l) {
        float2 v = np2[(size_t)l*256];
        float w0=sw[0][l], w1=sw[1][l], w2=sw[2][l], w3=sw[3][l], w4=sw[4][l];
        a0.x += w0*v.x; a0.y += w0*v.y;
        a1.x += w1*v.x; a1.y += w1*v.y;
        a2.x += w2*v.x; a2.y += w2*v.y;
        a3.x += w3*v.x; a3.y += w3*v.y;
        a4.x += w4*v.x; a4.y += w4*v.y;
    }
    ((float2*)(Q + (size_t)(b*C_+0)*D_))[t] = a0;
    ((float2*)(Q + (size_t)(b*C_+1)*D_))[t] = a1;
    ((float2*)(Q + (size_t)(b*C_+2)*D_))[t] = a2;
    ((float2*)(Q + (size_t)(b*C_+3)*D_))[t] = a3;
    ((float2*)(Q + (size_t)(b*C_+4)*D_))[t] = a4;
}

// K5: pw_raw[b,c,j] = (1/||tex[b,j]||) * dot(tex[b,j,:], Q[b,c,:])  [main stream #1]
__global__ void k_pw(const float* __restrict__ tex, const float* __restrict__ Q,
                     float* __restrict__ pw) {
    int j = blockIdx.x, b = blockIdx.y, lane = threadIdx.x;
    const float4* t4 = (const float4*)(tex + ((size_t)b*J_ + j)*D_);
    float4 a = t4[lane], a2 = t4[lane+64];
    float ss = dot4(a,a) + dot4(a2,a2);
    ss = wave_sum(ss);
    float inv = 1.f / fmaxf(sqrtf(ss), 1e-12f);
    float keep = 0.f;
#pragma unroll
    for (int c = 0; c < C_; ++c) {
        const float4* q4 = (const float4*)(Q + (size_t)(b*C_+c)*D_);
        float s = dot4(a, q4[lane]) + dot4(a2, q4[lane+64]);
        s = wave_sum(s);
        if (lane == c) keep = s * inv;
    }
    if (lane < C_) pw[((size_t)(b*C_+lane))*J_ + j] = keep;
}

// K6: softmax over j per (b,c), in place
__global__ void k_softmax(float* __restrict__ pw) {
    int bc = blockIdx.x;
    float* row = pw + (size_t)bc*J_;
    int t = threadIdx.x;
    __shared__ float red[256];
    float m = -1e30f;
    for (int j = t; j < J_; j += 256) m = fmaxf(m, row[j]);
    red[t] = m; __syncthreads();
    for (int s = 128; s > 0; s >>= 1) { if (t < s) red[t] = fmaxf(red[t], red[t+s]); __syncthreads(); }
    m = red[0]; __syncthreads();
    float sum = 0.f;
    for (int j = t; j < J_; j += 256) sum += expf(row[j] - m);
    red[t] = sum; __syncthreads();
    for (int s = 128; s > 0; s >>= 1) { if (t < s) red[t] += red[t+s]; __syncthreads(); }
    float inv = 1.f / red[0];
    for (int j = t; j < J_; j += 256) row[j] = expf(row[j] - m) * inv;
}

// K7: partial ftf over j-chunks  [main stream #2]
// part[chunk][b][c][d] = sum_{j in chunk} tex[b,j,d] * pw[b,c,j]
__global__ void k_ftf_part(const float* __restrict__ tex, const float* __restrict__ pw,
                           float* __restrict__ part) {
    int chunk = blockIdx.x, b = blockIdx.y;
    int t = threadIdx.x;                 // 512
    int j0 = chunk*JC_;
    int jn = min(JC_, J_ - j0);
    __shared__ float sw[C_][JC_];
    if (t < C_*JC_) {
        int c = t >> 6, jj = t & 63;
        sw[c][jj] = (jj < jn) ? pw[((size_t)(b*C_+c))*J_ + j0 + jj] : 0.f;
    }
    __syncthreads();
    float acc0=0.f, acc1=0.f, acc2=0.f, acc3=0.f, acc4=0.f;
    const float* tp = tex + ((size_t)b*J_ + j0)*D_ + t;
    for (int jj = 0; jj < jn; ++jj) {
        float v = tp[(size_t)jj*D_];
        acc0 += v*sw[0][jj]; acc1 += v*sw[1][jj]; acc2 += v*sw[2][jj];
        acc3 += v*sw[3][jj]; acc4 += v*sw[4][jj];
    }
    size_t base = (((size_t)chunk*B_ + b)*C_)*D_ + t;
    part[base          ] = acc0;
    part[base +   (size_t)D_] = acc1;
    part[base + 2*(size_t)D_] = acc2;
    part[base + 3*(size_t)D_] = acc3;
    part[base + 4*(size_t)D_] = acc4;
}

// K9: (fused reduce) fused[bc,d] = sum_ch part * eot; then fq[b,c,k] = dot(fused, qw[k]) + qb[k]
__global__ void k_fq(const float* __restrict__ part, const float* __restrict__ eot,
                     const float* __restrict__ qw, const float* __restrict__ qb,
                     float* __restrict__ fq) {
    int bc = blockIdx.x; int b = bc / C_;
    __shared__ float sf[D_];
    int t = threadIdx.x;                 // 256
    float s0 = 0.f, s1 = 0.f;
    for (int ch = 0; ch < NCH_; ++ch) {
        const float* p = part + ((size_t)ch*(B_*C_) + bc)*D_;
        s0 += p[t]; s1 += p[t+256];
    }
    sf[t]     = s0 * eot[b*D_ + t];
    sf[t+256] = s1 * eot[b*D_ + t + 256];
    __syncthreads();
    int wave = t >> 6, lane = t & 63;
    float4 f1 = ((const float4*)sf)[lane];
    float4 f2 = ((const float4*)sf)[lane+64];
    for (int k = wave; k < 224; k += 4) {
        const float4* w4 = (const float4*)(qw + (size_t)k*D_);
        float s = dot4(f1, w4[lane]) + dot4(f2, w4[lane+64]);
        s = wave_sum(s);
        if (lane == 0) fq[bc*224 + k] = s + qb[k];
    }
}

// K10: cond_maps — o-major: wave per o, all 5 conditions per weight-row read.
__global__ void k_condmaps(const float* __restrict__ fc, const float* __restrict__ cw,
                           const float* __restrict__ cb, float* __restrict__ cm) {
    __shared__ float sfc[C_*D_];
    int t = threadIdx.x;
    for (int i = t; i < C_*D_; i += 256) sfc[i] = fc[i];
    __syncthreads();
    int o = blockIdx.x*4 + (t >> 6);
    if (o >= 5488) return;
    int lane = t & 63;
    const float4* w4 = (const float4*)(cw + (size_t)o*D_);
    float4 wa = w4[lane], wb = w4[lane+64];
    float bias = cb[o];
    float keep = 0.f;
#pragma unroll
    for (int c = 0; c < C_; ++c) {
        const float4* f4 = (const float4*)(sfc + c*D_);
        float s = dot4(wa, f4[lane]) + dot4(wb, f4[lane+64]);
        s = wave_sum(s);
        if (lane == c) keep = s;
    }
    if (lane < C_) cm[lane*5488 + o] = keep + bias;
}

// K12: all four 3x3 SAME convs on [C,112,7,7].
// Thread = (output-channel o_comb, row y, channel-quarter chq); computes 7 x-outputs.
// LDS: padded image [112][9 rows][12 floats] (9x9 valid, zero border), 16B-aligned rows.
// grid: dim3(75, C_), block 256.  chq partials reduced via shfl_xor (lanes adjacent).
__global__ void k_conv(const float* __restrict__ cm,
                       const float* __restrict__ w1, const float* __restrict__ bb1,
                       const float* __restrict__ w2, const float* __restrict__ bb2,
                       const float* __restrict__ w3, const float* __restrict__ bb3,
                       const float* __restrict__ w4, const float* __restrict__ bb4,
                       float* __restrict__ o1, float* __restrict__ o2,
                       float* __restrict__ o3, float* __restrict__ o4) {
    __shared__ float im[112*108];        // 48384 B: ch stride 108 = 9 rows * 12
    int c = blockIdx.y;
    int t = threadIdx.x;
    for (int i = t; i < 112*108; i += 256) im[i] = 0.f;
    __syncthreads();
    const float* cmc = cm + c*5488;
    for (int i = t; i < 112*49; i += 256) {
        int ch = i / 49, yx = i - ch*49;
        int y = yx / 7, x = yx - y*7;
        im[ch*108 + (y+1)*12 + (x+1)] = cmc[i];
    }
    __syncthreads();

    int oy  = blockIdx.x*64 + (t >> 2);  // < 680*7 = 4760
    int chq = t & 3;
    if (oy >= 4760) return;
    int o_comb = oy / 7, y = oy - o_comb*7;

    const float* w; const float* bias; float* outp; int o;
    if      (o_comb < 512) { w=w1; bias=bb1; outp=o1 + (size_t)c*512*49; o=o_comb; }
    else if (o_comb < 640) { w=w2; bias=bb2; outp=o2 + (size_t)c*128*49; o=o_comb-512; }
    else if (o_comb < 672) { w=w3; bias=bb3; outp=o3 + (size_t)c*32*49;  o=o_comb-640; }
    else                   { w=w4; bias=bb4; outp=o4 + (size_t)c*8*49;   o=o_comb-672; }

    float ac0=0,ac1=0,ac2=0,ac3=0,ac4=0,ac5=0,ac6=0;
    const float* wbase = w + ((size_t)o*112 + chq*28)*9;
    const float* imc   = im + (chq*28)*108 + y*12;   // padded rows y..y+2 for output row y

#pragma unroll 2
    for (int ch = 0; ch < 28; ++ch) {
        const float* wk = wbase + ch*9;
        const float* ii = imc + ch*108;
        float w0=wk[0],w1_=wk[1],w2_=wk[2],w3_=wk[3],w4_=wk[4],w5_=wk[5],w6_=wk[6],w7_=wk[7],w8_=wk[8];
#pragma unroll
        for (int ky = 0; ky < 3; ++ky) {
            const float* row = ii + ky*12;
            float4 ra = *(const float4*)(row);
            float4 rb = *(const float4*)(row + 4);
            float  rc = row[8];
            float r0=ra.x,r1=ra.y,r2=ra.z,r3=ra.w,r4=rb.x,r5=rb.y,r6=rb.z,r7=rb.w,r8=rc;
            float wk0 = (ky==0)?w0:((ky==1)?w3_:w6_);
            float wk1 = (ky==0)?w1_:((ky==1)?w4_:w7_);
            float wk2 = (ky==0)?w2_:((ky==1)?w5_:w8_);
            ac0 += r0*wk0 + r1*wk1 + r2*wk2;
            ac1 += r1*wk0 + r2*wk1 + r3*wk2;
            ac2 += r2*wk0 + r3*wk1 + r4*wk2;
            ac3 += r3*wk0 + r4*wk1 + r5*wk2;
            ac4 += r4*wk0 + r5*wk1 + r6*wk2;
            ac5 += r5*wk0 + r6*wk1 + r7*wk2;
            ac6 += r6*wk0 + r7*wk1 + r8*wk2;
        }
    }
    // reduce across the 4 chq lanes (adjacent lanes)
    ac0 += __shfl_xor(ac0,1,64); ac0 += __shfl_xor(ac0,2,64);
    ac1 += __shfl_xor(ac1,1,64); ac1 += __shfl_xor(ac1,2,64);
    ac2 += __shfl_xor(ac2,1,64); ac2 += __shfl_xor(ac2,2,64);
    ac3 += __shfl_xor(ac3,1,64); ac3 += __shfl_xor(ac3,2,64);
    ac4 += __shfl_xor(ac4,1,64); ac4 += __shfl_xor(ac4,2,64);
    ac5 += __shfl_xor(ac5,1,64); ac5 += __shfl_xor(ac5,2,64);
    ac6 += __shfl_xor(ac6,1,64); ac6 += __shfl_xor(ac6,2,64);
    if (chq == 0) {
        float bo = bias[o];
        float* dst = outp + o*49 + y*7;
        dst[0]=ac0+bo; dst[1]=ac1+bo; dst[2]=ac2+bo; dst[3]=ac3+bo;
        dst[4]=ac4+bo; dst[5]=ac5+bo; dst[6]=ac6+bo;
    }
}

// K13: fused pooled + hypernet fc biases, one block per condition c.
// fcb layout: [0,560) fc1b | [560,840) fc2b | [840,980) fc3b | [980,1050) fc4b
//             [1050,1120) fc5w | [1120,1125) fc5b
__global__ void k_hyper(const float* __restrict__ cm,
                        const float* __restrict__ w1b, const float* __restrict__ b1b,
                        const float* __restrict__ w2b, const float* __restrict__ b2b,
                        const float* __restrict__ w3b, const float* __restrict__ b3b,
                        const float* __restrict__ w4b, const float* __restrict__ b4b,
                        const float* __restrict__ w5w, const float* __restrict__ b5w,
                        const float* __restrict__ w5b, const float* __restrict__ b5b,
                        float* __restrict__ fcb) {
    __shared__ float sp[112];
    int c = blockIdx.x;
    int t = threadIdx.x;                 // 256
    if (t < 112) {
        const float* p = cm + c*5488 + t*49;
        float s = 0.f;
        for (int k = 0; k < 49; ++k) s += p[k];
        sp[t] = s * (1.f/49.f);
    }
    __syncthreads();
    if (t >= 225) return;
    int rel = t;
    const float* w; const float* bb; int nout; int base;
    if      (rel < 112) {            w=w1b; bb=b1b; nout=112; base=0; }
    else if (rel < 168) { rel-=112;  w=w2b; bb=b2b; nout=56;  base=560; }
    else if (rel < 196) { rel-=168;  w=w3b; bb=b3b; nout=28;  base=840; }
    else if (rel < 210) { rel-=196;  w=w4b; bb=b4b; nout=14;  base=980; }
    else if (rel < 224) { rel-=210;  w=w5w; bb=b5w; nout=14;  base=1050; }
    else                { rel-=224;  w=w5b; bb=b5b; nout=1;   base=1120; }
    float s = bb[rel];
    const float* wr = w + rel*112;
    for (int i = 0; i < 112; ++i) s += sp[i]*wr[i];
    fcb[base + c*nout + rel] = s;
}

// K14: TargetNet per (b,c): 4 sigmoid layers + linear head -> out[b*C+c]
__global__ void k_target(const float* __restrict__ fq,
                         const float* __restrict__ g1w, const float* __restrict__ g2w,
                         const float* __restrict__ g3w, const float* __restrict__ g4w,
                         const float* __restrict__ fcb, float* __restrict__ out) {
    int c = blockIdx.x, b = blockIdx.y;
    __shared__ float sa[224], sb[112];
    int t = threadIdx.x;                 // 128
    for (int k = t; k < 224; k += 128) sa[k] = fq[(size_t)(b*C_+c)*224 + k];
    __syncthreads();
    if (t < 112) {
        const float* w = g1w + (size_t)c*25088 + t*224;
        float s = fcb[c*112 + t];
        for (int k = 0; k < 224; ++k) s += w[k]*sa[k];
        sb[t] = 1.f/(1.f+expf(-s));
    }
    __syncthreads();
    if (t < 56) {
        const float* w = g2w + (size_t)c*6272 + t*112;
        float s = fcb[560 + c*56 + t];
        for (int k = 0; k < 112; ++k) s += w[k]*sb[k];
        sa[t] = 1.f/(1.f+expf(-s));
    }
    __syncthreads();
    if (t < 28) {
        const float* w = g3w + (size_t)c*1568 + t*56;
        float s = fcb[840 + c*28 + t];
        for (int k = 0; k < 56; ++k) s += w[k]*sa[k];
        sb[t] = 1.f/(1.f+expf(-s));
    }
    __syncthreads();
    if (t < 14) {
        const float* w = g4w + (size_t)c*392 + t*28;
        float s = fcb[980 + c*14 + t];
        for (int k = 0; k < 28; ++k) s += w[k]*sb[k];
        sa[t] = 1.f/(1.f+expf(-s));
    }
    __syncthreads();
    if (t == 0) {
        float s = fcb[1120 + c];
        for (int p = 0; p < 14; ++p) s += sa[p]*fcb[1050 + c*14 + p];
        out[b*C_ + c] = s;
    }
}

extern "C" void kernel_launch(void* const* d_in, const int* in_sizes, int n_in,
                              void* d_out, int out_size, void* d_ws, size_t ws_size,
                              hipStream_t stream) {
    (void)in_sizes; (void)n_in; (void)out_size; (void)ws_size;
    const float* tex   = (const float*)d_in[0];
    const float* fp    = (const float*)d_in[1];
    const float* eot   = (const float*)d_in[2];
    const float* fcond = (const float*)d_in[3];
    const float* qw    = (const float*)d_in[4];
    const float* qb    = (const float*)d_in[5];
    const float* cw    = (const float*)d_in[6];
    const float* cb    = (const float*)d_in[7];
    const float* w1c   = (const float*)d_in[8];  const float* b1c = (const float*)d_in[9];
    const float* w2c   = (const float*)d_in[10]; const float* b2c = (const float*)d_in[11];
    const float* w3c   = (const float*)d_in[12]; const float* b3c = (const float*)d_in[13];
    const float* w4c   = (const float*)d_in[14]; const float* b4c = (const float*)d_in[15];
    const float* f1bw  = (const float*)d_in[16]; const float* f1bb = (const float*)d_in[17];
    const float* f2bw  = (const float*)d_in[18]; const float* f2bb = (const float*)d_in[19];
    const float* f3bw  = (const float*)d_in[20]; const float* f3bb = (const float*)d_in[21];
    const float* f4bw  = (const float*)d_in[22]; const float* f4bb = (const float*)d_in[23];
    const float* f5ww  = (const float*)d_in[24]; const float* f5wb = (const float*)d_in[25];
    const float* f5bw  = (const float*)d_in[26]; const float* f5bb = (const float*)d_in[27];
    float* out = (float*)d_out;

    float* ws     = (float*)d_ws;
    float* fn     = ws;                         // 2560
    float* npb    = fn + 2560;                  // 1261568
    float* sc     = npb + 1261568;              // 12320
    float* Qb     = sc + 12320;                 // 81920
    float* pw     = Qb + 81920;                 // 189120
    float* part   = pw + 189120;                // NCH*81920
    float* fqb    = part + (size_t)NCH_*81920;  // 35840
    float* cm     = fqb + 35840;                // 27440
    float* g1w    = cm + 27440;                 // 125440
    float* g2w    = g1w + 125440;               // 31360
    float* g3w    = g2w + 31360;                // 7840
    float* g4w    = g3w + 7840;                 // 1960
    float* fcb    = g4w + 1960;                 // 1125

    // condition path
    k_fn_loss<<<1, 320, 0, stream>>>(fcond, fn, out + B_*C_);
    k_condmaps<<<1372, 256, 0, stream>>>(fcond, cw, cb, cm);
    k_conv<<<dim3(75, C_), 256, 0, stream>>>(cm, w1c, b1c, w2c, b2c, w3c, b3c, w4c, b4c,
                                             g1w, g2w, g3w, g4w);
    k_hyper<<<C_, 256, 0, stream>>>(cm, f1bw, f1bb, f2bw, f2bb, f3bw, f3bb,
                                    f4bw, f4bb, f5ww, f5wb, f5bw, f5bb, fcb);

    // main path
    k_norm_prompt<<<B_*L_, 64, 0, stream>>>(fp, npb);
    k_sim_cond<<<B_*C_*L_, 64, 0, stream>>>(npb, fn, sc);
    k_Q<<<B_, 256, 0, stream>>>(npb, sc, Qb);
    k_pw<<<dim3(J_, B_), 64, 0, stream>>>(tex, Qb, pw);
    k_softmax<<<B_*C_, 256, 0, stream>>>(pw);
    k_ftf_part<<<dim3(NCH_, B_), 512, 0, stream>>>(tex, pw, part);
    k_fq<<<B_*C_, 256, 0, stream>>>(part, eot, qw, qb, fqb);
    k_target<<<dim3(C_, B_), 128, 0, stream>>>(fqb, g1w, g2w, g3w, g4w, fcb, out);
}

// Round 4
// 131.652 us; speedup vs baseline: 2.2354x; 1.1400x over previous
//
#include <hip/hip_runtime.h>
#include <hip/hip_bf16.h>
#include <math.h>

#define B_   32
#define J_   1182      // V*P = 6*197
#define D_   512
#define L_   77
#define C_   5
#define JC_  64
#define NCH_ 19        // ceil(1182/64)

__device__ __forceinline__ float dot4(float4 a, float4 b) {
    return a.x*b.x + a.y*b.y + a.z*b.z + a.w*b.w;
}

__device__ __forceinline__ float wave_sum(float v) {
#pragma unroll
    for (int off = 32; off > 0; off >>= 1) v += __shfl_xor(v, off, 64);
    return v;
}

// K1: normalize feature_condition rows -> fn; loss_dis -> out[160]
__global__ void k_fn_loss(const float* __restrict__ fc, float* __restrict__ fn,
                          float* __restrict__ loss_out) {
    int wave = threadIdx.x >> 6, lane = threadIdx.x & 63;
    if (wave < C_) {
        float ss = 0.f;
        for (int d = lane; d < D_; d += 64) { float v = fc[wave*D_+d]; ss += v*v; }
        ss = wave_sum(ss);
        float inv = 1.f / fmaxf(sqrtf(ss), 1e-12f);
        for (int d = lane; d < D_; d += 64) fn[wave*D_+d] = fc[wave*D_+d]*inv;
    }
    __syncthreads();
    if (wave == 0) {
        float acc = 0.f;
        for (int i = 0; i < C_; ++i)
            for (int j = i+1; j < C_; ++j) {
                float p = 0.f;
                for (int d = lane; d < D_; d += 64) p += fn[i*D_+d]*fn[j*D_+d];
                p = wave_sum(p);
                acc += fmaxf(p, 0.f);
            }
        if (lane == 0) *loss_out = acc * (1.f/10.f);
    }
}

// K2: normalize feature_prompt rows (B*L rows of 512)
__global__ void k_norm_prompt(const float* __restrict__ fp, float* __restrict__ npb) {
    int row = blockIdx.x, lane = threadIdx.x;
    const float4* src = (const float4*)(fp + (size_t)row*D_);
    float4 a = src[lane], b = src[lane+64];
    float ss = dot4(a,a) + dot4(b,b);
    ss = wave_sum(ss);
    float inv = 1.f / fmaxf(sqrtf(ss), 1e-12f);
    a.x*=inv; a.y*=inv; a.z*=inv; a.w*=inv;
    b.x*=inv; b.y*=inv; b.z*=inv; b.w*=inv;
    float4* dst = (float4*)(npb + (size_t)row*D_);
    dst[lane] = a; dst[lane+64] = b;
}

// K3: sim_cond[b,c,l] = dot(np_prompt[b,l,:], fn[c,:])
__global__ void k_sim_cond(const float* __restrict__ npb, const float* __restrict__ fn,
                           float* __restrict__ sc) {
    int idx = blockIdx.x;               // ((b*C)+c)*L + l
    int l = idx % L_; int t = idx / L_; int c = t % C_; int b = t / C_;
    int lane = threadIdx.x;
    const float4* p = (const float4*)(npb + ((size_t)(b*L_ + l))*D_);
    const float4* q = (const float4*)(fn + c*D_);
    float s = dot4(p[lane], q[lane]) + dot4(p[lane+64], q[lane+64]);
    s = wave_sum(s);
    if (lane == 0) sc[idx] = s;
}

// K4: Q[b,c,d] = sum_l sim_cond[b,c,l] * np_prompt[b,l,d]
// one block per b, thread owns float2 (dims 2t, 2t+1), 5 accumulators
__global__ void k_Q(const float* __restrict__ npb, const float* __restrict__ sc,
                    float* __restrict__ Q) {
    __shared__ float sw[C_][80];
    int b = blockIdx.x;
    int t = threadIdx.x;                 // 256
    for (int i = t; i < C_*L_; i += 256) { int c = i/L_, l = i - c*L_; sw[c][l] = sc[(b*C_+c)*L_ + l]; }
    __syncthreads();
    float2 a0={0,0}, a1={0,0}, a2={0,0}, a3={0,0}, a4={0,0};
    const float2* np2 = (const float2*)(npb + (size_t)b*L_*D_) + t;
    for (int l = 0; l < L_; ++l) {
        float2 v = np2[(size_t)l*256];
        float w0=sw[0][l], w1=sw[1][l], w2=sw[2][l], w3=sw[3][l], w4=sw[4][l];
        a0.x += w0*v.x; a0.y += w0*v.y;
        a1.x += w1*v.x; a1.y += w1*v.y;
        a2.x += w2*v.x; a2.y += w2*v.y;
        a3.x += w3*v.x; a3.y += w3*v.y;
        a4.x += w4*v.x; a4.y += w4*v.y;
    }
    ((float2*)(Q + (size_t)(b*C_+0)*D_))[t] = a0;
    ((float2*)(Q + (size_t)(b*C_+1)*D_))[t] = a1;
    ((float2*)(Q + (size_t)(b*C_+2)*D_))[t] = a2;
    ((float2*)(Q + (size_t)(b*C_+3)*D_))[t] = a3;
    ((float2*)(Q + (size_t)(b*C_+4)*D_))[t] = a4;
}

// K5: pw_raw[b,c,j] = (1/||tex[b,j]||) * dot(tex[b,j,:], Q[b,c,:])  [main stream #1]
__global__ void k_pw(const float* __restrict__ tex, const float* __restrict__ Q,
                     float* __restrict__ pw) {
    int j = blockIdx.x, b = blockIdx.y, lane = threadIdx.x;
    const float4* t4 = (const float4*)(tex + ((size_t)b*J_ + j)*D_);
    float4 a = t4[lane], a2 = t4[lane+64];
    float ss = dot4(a,a) + dot4(a2,a2);
    ss = wave_sum(ss);
    float inv = 1.f / fmaxf(sqrtf(ss), 1e-12f);
    float keep = 0.f;
#pragma unroll
    for (int c = 0; c < C_; ++c) {
        const float4* q4 = (const float4*)(Q + (size_t)(b*C_+c)*D_);
        float s = dot4(a, q4[lane]) + dot4(a2, q4[lane+64]);
        s = wave_sum(s);
        if (lane == c) keep = s * inv;
    }
    if (lane < C_) pw[((size_t)(b*C_+lane))*J_ + j] = keep;
}

// K6: softmax over j per (b,c), in place
__global__ void k_softmax(float* __restrict__ pw) {
    int bc = blockIdx.x;
    float* row = pw + (size_t)bc*J_;
    int t = threadIdx.x;
    __shared__ float red[256];
    float m = -1e30f;
    for (int j = t; j < J_; j += 256) m = fmaxf(m, row[j]);
    red[t] = m; __syncthreads();
    for (int s = 128; s > 0; s >>= 1) { if (t < s) red[t] = fmaxf(red[t], red[t+s]); __syncthreads(); }
    m = red[0]; __syncthreads();
    float sum = 0.f;
    for (int j = t; j < J_; j += 256) sum += expf(row[j] - m);
    red[t] = sum; __syncthreads();
    for (int s = 128; s > 0; s >>= 1) { if (t < s) red[t] += red[t+s]; __syncthreads(); }
    float inv = 1.f / red[0];
    for (int j = t; j < J_; j += 256) row[j] = expf(row[j] - m) * inv;
}

// K7: partial ftf over j-chunks  [main stream #2]
// part[chunk][b][c][d] = sum_{j in chunk} tex[b,j,d] * pw[b,c,j]
__global__ void k_ftf_part(const float* __restrict__ tex, const float* __restrict__ pw,
                           float* __restrict__ part) {
    int chunk = blockIdx.x, b = blockIdx.y;
    int t = threadIdx.x;                 // 512
    int j0 = chunk*JC_;
    int jn = min(JC_, J_ - j0);
    __shared__ float sw[C_][JC_];
    if (t < C_*JC_) {
        int c = t >> 6, jj = t & 63;
        sw[c][jj] = (jj < jn) ? pw[((size_t)(b*C_+c))*J_ + j0 + jj] : 0.f;
    }
    __syncthreads();
    float acc0=0.f, acc1=0.f, acc2=0.f, acc3=0.f, acc4=0.f;
    const float* tp = tex + ((size_t)b*J_ + j0)*D_ + t;
    for (int jj = 0; jj < jn; ++jj) {
        float v = tp[(size_t)jj*D_];
        acc0 += v*sw[0][jj]; acc1 += v*sw[1][jj]; acc2 += v*sw[2][jj];
        acc3 += v*sw[3][jj]; acc4 += v*sw[4][jj];
    }
    size_t base = (((size_t)chunk*B_ + b)*C_)*D_ + t;
    part[base          ] = acc0;
    part[base +   (size_t)D_] = acc1;
    part[base + 2*(size_t)D_] = acc2;
    part[base + 3*(size_t)D_] = acc3;
    part[base + 4*(size_t)D_] = acc4;
}

// K9: fused fq + TargetNet per (b,c) block.
// Phase 1: sf[d] = (sum_ch part[ch][bc][d]) * eot[b][d]        (LDS, no shuffle)
// Phase 2: fq[k]  = dot(sf, qw[k]) + qb[k], one THREAD per k   (no shuffle)
// Phase 3: 4 sigmoid layers + linear head -> out[b*C+c]
__global__ void k_fq_target(const float* __restrict__ part, const float* __restrict__ eot,
                            const float* __restrict__ qw, const float* __restrict__ qb,
                            const float* __restrict__ g1w, const float* __restrict__ g2w,
                            const float* __restrict__ g3w, const float* __restrict__ g4w,
                            const float* __restrict__ fcb, float* __restrict__ out) {
    int bc = blockIdx.x; int b = bc / C_; int c = bc - b*C_;
    __shared__ float sf[D_];
    __shared__ float sa[224], sb[112];
    int t = threadIdx.x;                 // 256

    // phase 1: chunk reduce + eot
    float s0 = 0.f, s1 = 0.f;
    for (int ch = 0; ch < NCH_; ++ch) {
        const float* p = part + ((size_t)ch*(B_*C_) + bc)*D_;
        s0 += p[t]; s1 += p[t+256];
    }
    sf[t]     = s0 * eot[b*D_ + t];
    sf[t+256] = s1 * eot[b*D_ + t + 256];
    __syncthreads();

    // phase 2: thread t owns output k=t (t<224); 128 float4 FMAs, sf via LDS broadcast
    if (t < 224) {
        const float4* w4 = (const float4*)(qw + (size_t)t*D_);
        const float4* s4 = (const float4*)sf;
        float acc = 0.f;
#pragma unroll 4
        for (int i = 0; i < 128; ++i) acc += dot4(s4[i], w4[i]);
        sa[t] = acc + qb[t];
    }
    __syncthreads();

    // phase 3: TargetNet
    if (t < 112) {
        const float* w = g1w + (size_t)c*25088 + t*224;
        float s = fcb[c*112 + t];
        for (int k = 0; k < 224; ++k) s += w[k]*sa[k];
        sb[t] = 1.f/(1.f+expf(-s));
    }
    __syncthreads();
    if (t < 56) {
        const float* w = g2w + (size_t)c*6272 + t*112;
        float s = fcb[560 + c*56 + t];
        for (int k = 0; k < 112; ++k) s += w[k]*sb[k];
        sa[t] = 1.f/(1.f+expf(-s));
    }
    __syncthreads();
    if (t < 28) {
        const float* w = g3w + (size_t)c*1568 + t*56;
        float s = fcb[840 + c*28 + t];
        for (int k = 0; k < 56; ++k) s += w[k]*sa[k];
        sb[t] = 1.f/(1.f+expf(-s));
    }
    __syncthreads();
    if (t < 14) {
        const float* w = g4w + (size_t)c*392 + t*28;
        float s = fcb[980 + c*14 + t];
        for (int k = 0; k < 28; ++k) s += w[k]*sb[k];
        sa[t] = 1.f/(1.f+expf(-s));
    }
    __syncthreads();
    if (t == 0) {
        float s = fcb[1120 + c];
        for (int p = 0; p < 14; ++p) s += sa[p]*fcb[1050 + c*14 + p];
        out[b*C_ + c] = s;
    }
}

// K10: cond_maps — o-major: wave per o, all 5 conditions per weight-row read.
__global__ void k_condmaps(const float* __restrict__ fc, const float* __restrict__ cw,
                           const float* __restrict__ cb, float* __restrict__ cm) {
    __shared__ float sfc[C_*D_];
    int t = threadIdx.x;
    for (int i = t; i < C_*D_; i += 256) sfc[i] = fc[i];
    __syncthreads();
    int o = blockIdx.x*4 + (t >> 6);
    if (o >= 5488) return;
    int lane = t & 63;
    const float4* w4 = (const float4*)(cw + (size_t)o*D_);
    float4 wa = w4[lane], wb = w4[lane+64];
    float bias = cb[o];
    float keep = 0.f;
#pragma unroll
    for (int c = 0; c < C_; ++c) {
        const float4* f4 = (const float4*)(sfc + c*D_);
        float s = dot4(wa, f4[lane]) + dot4(wb, f4[lane+64]);
        s = wave_sum(s);
        if (lane == c) keep = s;
    }
    if (lane < C_) cm[lane*5488 + o] = keep + bias;
}

// K12: all four 3x3 SAME convs on [C,112,7,7].
// Thread = (output-channel o_comb, row y, channel-quarter chq); computes 7 x-outputs.
// LDS: padded image [112][9 rows][12 floats] (9x9 valid, zero border), 16B-aligned rows.
// grid: dim3(75, C_), block 256.  chq partials reduced via shfl_xor (lanes adjacent).
__global__ void k_conv(const float* __restrict__ cm,
                       const float* __restrict__ w1, const float* __restrict__ bb1,
                       const float* __restrict__ w2, const float* __restrict__ bb2,
                       const float* __restrict__ w3, const float* __restrict__ bb3,
                       const float* __restrict__ w4, const float* __restrict__ bb4,
                       float* __restrict__ o1, float* __restrict__ o2,
                       float* __restrict__ o3, float* __restrict__ o4) {
    __shared__ float im[112*108];        // 48384 B: ch stride 108 = 9 rows * 12
    int c = blockIdx.y;
    int t = threadIdx.x;
    for (int i = t; i < 112*108; i += 256) im[i] = 0.f;
    __syncthreads();
    const float* cmc = cm + c*5488;
    for (int i = t; i < 112*49; i += 256) {
        int ch = i / 49, yx = i - ch*49;
        int y = yx / 7, x = yx - y*7;
        im[ch*108 + (y+1)*12 + (x+1)] = cmc[i];
    }
    __syncthreads();

    int oy  = blockIdx.x*64 + (t >> 2);  // < 680*7 = 4760
    int chq = t & 3;
    if (oy >= 4760) return;
    int o_comb = oy / 7, y = oy - o_comb*7;

    const float* w; const float* bias; float* outp; int o;
    if      (o_comb < 512) { w=w1; bias=bb1; outp=o1 + (size_t)c*512*49; o=o_comb; }
    else if (o_comb < 640) { w=w2; bias=bb2; outp=o2 + (size_t)c*128*49; o=o_comb-512; }
    else if (o_comb < 672) { w=w3; bias=bb3; outp=o3 + (size_t)c*32*49;  o=o_comb-640; }
    else                   { w=w4; bias=bb4; outp=o4 + (size_t)c*8*49;   o=o_comb-672; }

    float ac0=0,ac1=0,ac2=0,ac3=0,ac4=0,ac5=0,ac6=0;
    const float* wbase = w + ((size_t)o*112 + chq*28)*9;
    const float* imc   = im + (chq*28)*108 + y*12;   // padded rows y..y+2 for output row y

#pragma unroll 2
    for (int ch = 0; ch < 28; ++ch) {
        const float* wk = wbase + ch*9;
        const float* ii = imc + ch*108;
        float w0=wk[0],w1_=wk[1],w2_=wk[2],w3_=wk[3],w4_=wk[4],w5_=wk[5],w6_=wk[6],w7_=wk[7],w8_=wk[8];
#pragma unroll
        for (int ky = 0; ky < 3; ++ky) {
            const float* row = ii + ky*12;
            float4 ra = *(const float4*)(row);
            float4 rb = *(const float4*)(row + 4);
            float  rc = row[8];
            float r0=ra.x,r1=ra.y,r2=ra.z,r3=ra.w,r4=rb.x,r5=rb.y,r6=rb.z,r7=rb.w,r8=rc;
            float wk0 = (ky==0)?w0:((ky==1)?w3_:w6_);
            float wk1 = (ky==0)?w1_:((ky==1)?w4_:w7_);
            float wk2 = (ky==0)?w2_:((ky==1)?w5_:w8_);
            ac0 += r0*wk0 + r1*wk1 + r2*wk2;
            ac1 += r1*wk0 + r2*wk1 + r3*wk2;
            ac2 += r2*wk0 + r3*wk1 + r4*wk2;
            ac3 += r3*wk0 + r4*wk1 + r5*wk2;
            ac4 += r4*wk0 + r5*wk1 + r6*wk2;
            ac5 += r5*wk0 + r6*wk1 + r7*wk2;
            ac6 += r6*wk0 + r7*wk1 + r8*wk2;
        }
    }
    // reduce across the 4 chq lanes (adjacent lanes)
    ac0 += __shfl_xor(ac0,1,64); ac0 += __shfl_xor(ac0,2,64);
    ac1 += __shfl_xor(ac1,1,64); ac1 += __shfl_xor(ac1,2,64);
    ac2 += __shfl_xor(ac2,1,64); ac2 += __shfl_xor(ac2,2,64);
    ac3 += __shfl_xor(ac3,1,64); ac3 += __shfl_xor(ac3,2,64);
    ac4 += __shfl_xor(ac4,1,64); ac4 += __shfl_xor(ac4,2,64);
    ac5 += __shfl_xor(ac5,1,64); ac5 += __shfl_xor(ac5,2,64);
    ac6 += __shfl_xor(ac6,1,64); ac6 += __shfl_xor(ac6,2,64);
    if (chq == 0) {
        float bo = bias[o];
        float* dst = outp + o*49 + y*7;
        dst[0]=ac0+bo; dst[1]=ac1+bo; dst[2]=ac2+bo; dst[3]=ac3+bo;
        dst[4]=ac4+bo; dst[5]=ac5+bo; dst[6]=ac6+bo;
    }
}

// K13: fused pooled + hypernet fc biases, one block per condition c.
// fcb layout: [0,560) fc1b | [560,840) fc2b | [840,980) fc3b | [980,1050) fc4b
//             [1050,1120) fc5w | [1120,1125) fc5b
__global__ void k_hyper(const float* __restrict__ cm,
                        const float* __restrict__ w1b, const float* __restrict__ b1b,
                        const float* __restrict__ w2b, const float* __restrict__ b2b,
                        const float* __restrict__ w3b, const float* __restrict__ b3b,
                        const float* __restrict__ w4b, const float* __restrict__ b4b,
                        const float* __restrict__ w5w, const float* __restrict__ b5w,
                        const float* __restrict__ w5b, const float* __restrict__ b5b,
                        float* __restrict__ fcb) {
    __shared__ float sp[112];
    int c = blockIdx.x;
    int t = threadIdx.x;                 // 256
    if (t < 112) {
        const float* p = cm + c*5488 + t*49;
        float s = 0.f;
        for (int k = 0; k < 49; ++k) s += p[k];
        sp[t] = s * (1.f/49.f);
    }
    __syncthreads();
    if (t >= 225) return;
    int rel = t;
    const float* w; const float* bb; int nout; int base;
    if      (rel < 112) {            w=w1b; bb=b1b; nout=112; base=0; }
    else if (rel < 168) { rel-=112;  w=w2b; bb=b2b; nout=56;  base=560; }
    else if (rel < 196) { rel-=168;  w=w3b; bb=b3b; nout=28;  base=840; }
    else if (rel < 210) { rel-=196;  w=w4b; bb=b4b; nout=14;  base=980; }
    else if (rel < 224) { rel-=210;  w=w5w; bb=b5w; nout=14;  base=1050; }
    else                { rel-=224;  w=w5b; bb=b5b; nout=1;   base=1120; }
    float s = bb[rel];
    const float* wr = w + rel*112;
    for (int i = 0; i < 112; ++i) s += sp[i]*wr[i];
    fcb[base + c*nout + rel] = s;
}

extern "C" void kernel_launch(void* const* d_in, const int* in_sizes, int n_in,
                              void* d_out, int out_size, void* d_ws, size_t ws_size,
                              hipStream_t stream) {
    (void)in_sizes; (void)n_in; (void)out_size; (void)ws_size;
    const float* tex   = (const float*)d_in[0];
    const float* fp    = (const float*)d_in[1];
    const float* eot   = (const float*)d_in[2];
    const float* fcond = (const float*)d_in[3];
    const float* qw    = (const float*)d_in[4];
    const float* qb    = (const float*)d_in[5];
    const float* cw    = (const float*)d_in[6];
    const float* cb    = (const float*)d_in[7];
    const float* w1c   = (const float*)d_in[8];  const float* b1c = (const float*)d_in[9];
    const float* w2c   = (const float*)d_in[10]; const float* b2c = (const float*)d_in[11];
    const float* w3c   = (const float*)d_in[12]; const float* b3c = (const float*)d_in[13];
    const float* w4c   = (const float*)d_in[14]; const float* b4c = (const float*)d_in[15];
    const float* f1bw  = (const float*)d_in[16]; const float* f1bb = (const float*)d_in[17];
    const float* f2bw  = (const float*)d_in[18]; const float* f2bb = (const float*)d_in[19];
    const float* f3bw  = (const float*)d_in[20]; const float* f3bb = (const float*)d_in[21];
    const float* f4bw  = (const float*)d_in[22]; const float* f4bb = (const float*)d_in[23];
    const float* f5ww  = (const float*)d_in[24]; const float* f5wb = (const float*)d_in[25];
    const float* f5bw  = (const float*)d_in[26]; const float* f5bb = (const float*)d_in[27];
    float* out = (float*)d_out;

    float* ws     = (float*)d_ws;
    float* fn     = ws;                         // 2560
    float* npb    = fn + 2560;                  // 1261568
    float* sc     = npb + 1261568;              // 12320
    float* Qb     = sc + 12320;                 // 81920
    float* pw     = Qb + 81920;                 // 189120
    float* part   = pw + 189120;                // NCH*81920
    float* cm     = part + (size_t)NCH_*81920;  // 27440
    float* g1w    = cm + 27440;                 // 125440
    float* g2w    = g1w + 125440;               // 31360
    float* g3w    = g2w + 31360;                // 7840
    float* g4w    = g3w + 7840;                 // 1960
    float* fcb    = g4w + 1960;                 // 1125

    // condition path
    k_fn_loss<<<1, 320, 0, stream>>>(fcond, fn, out + B_*C_);
    k_condmaps<<<1372, 256, 0, stream>>>(fcond, cw, cb, cm);
    k_conv<<<dim3(75, C_), 256, 0, stream>>>(cm, w1c, b1c, w2c, b2c, w3c, b3c, w4c, b4c,
                                             g1w, g2w, g3w, g4w);
    k_hyper<<<C_, 256, 0, stream>>>(cm, f1bw, f1bb, f2bw, f2bb, f3bw, f3bb,
                                    f4bw, f4bb, f5ww, f5wb, f5bw, f5bb, fcb);

    // main path
    k_norm_prompt<<<B_*L_, 64, 0, stream>>>(fp, npb);
    k_sim_cond<<<B_*C_*L_, 64, 0, stream>>>(npb, fn, sc);
    k_Q<<<B_, 256, 0, stream>>>(npb, sc, Qb);
    k_pw<<<dim3(J_, B_), 64, 0, stream>>>(tex, Qb, pw);
    k_softmax<<<B_*C_, 256, 0, stream>>>(pw);
    k_ftf_part<<<dim3(NCH_, B_), 512, 0, stream>>>(tex, pw, part);
    k_fq_target<<<B_*C_, 256, 0, stream>>>(part, eot, qw, qb,
                                           g1w, g2w, g3w, g4w, fcb, out);
}